// Round 2
// baseline (1246.013 us; speedup 1.0000x reference)
//
#include <hip/hip_runtime.h>
#include <hip/hip_bf16.h>

// GCN: 3x (GEMM -> normalized-adjacency aggregation) -> mean pool -> classifier.
// Aggregation uses a per-call CSR (edges binned by dst) so it is gather-only
// (no f32 atomics). Self-loops handled analytically via dinv[n]^2 * h[n].

// ---------------- degree / dinv ----------------
__global__ __launch_bounds__(256) void init_degf(float* degf, int N) {
  int i = blockIdx.x * 256 + threadIdx.x;
  if (i < N) degf[i] = 1.0f;  // self-loop
}

__global__ __launch_bounds__(256) void deg_count(const int* __restrict__ dstIdx,
                                                 float* degf, int E) {
  int e = blockIdx.x * 256 + threadIdx.x;
  if (e < E) atomicAdd(&degf[dstIdx[e]], 1.0f);
}

__global__ __launch_bounds__(256) void dinv_k(const float* __restrict__ degf,
                                              float* __restrict__ dinv, int N) {
  int i = blockIdx.x * 256 + threadIdx.x;
  if (i < N) dinv[i] = rsqrtf(degf[i]);
}

// ---------------- exclusive scan of (deg-1) -> CSR offsets ----------------
__global__ __launch_bounds__(256) void scan_local(const float* __restrict__ degf,
                                                  int* __restrict__ offsets,
                                                  int* __restrict__ blockSums, int N) {
  __shared__ int lds[256];
  int t = threadIdx.x;
  int base = blockIdx.x * 1024 + t * 4;
  int c[4], s = 0;
#pragma unroll
  for (int i = 0; i < 4; i++) {
    int idx = base + i;
    c[i] = (idx < N) ? ((int)degf[idx] - 1) : 0;
    s += c[i];
  }
  lds[t] = s;
  __syncthreads();
  for (int d = 1; d < 256; d <<= 1) {
    int add = (t >= d) ? lds[t - d] : 0;
    __syncthreads();
    lds[t] += add;
    __syncthreads();
  }
  int incl = lds[t];
  int run = incl - s;  // exclusive prefix of this thread's 4
#pragma unroll
  for (int i = 0; i < 4; i++) {
    int idx = base + i;
    if (idx < N) offsets[idx] = run;
    run += c[i];
  }
  if (t == 255) blockSums[blockIdx.x] = incl;
}

__global__ __launch_bounds__(128) void scan_block(const int* __restrict__ blockSums,
                                                  int* __restrict__ blockOff, int nb) {
  __shared__ int lds[128];
  int t = threadIdx.x;
  int v = (t < nb) ? blockSums[t] : 0;
  lds[t] = v;
  __syncthreads();
  for (int d = 1; d < 128; d <<= 1) {
    int add = (t >= d) ? lds[t - d] : 0;
    __syncthreads();
    lds[t] += add;
    __syncthreads();
  }
  blockOff[t] = lds[t] - v;  // exclusive
}

__global__ __launch_bounds__(256) void scan_add(int* __restrict__ offsets,
                                                const int* __restrict__ blockOff, int N) {
  int i = blockIdx.x * 256 + threadIdx.x;
  if (i < N) offsets[i] += blockOff[i >> 10];
}

// ---------------- CSR fill: csr[pos] = {src, dinv[src]} ----------------
__global__ __launch_bounds__(256) void fill_csr(const int* __restrict__ ei,
                                                const float* __restrict__ dinv,
                                                const int* __restrict__ offsets,
                                                int* __restrict__ cursor,
                                                int2* __restrict__ csr, int E) {
  int e = blockIdx.x * 256 + threadIdx.x;
  if (e < E) {
    int s = ei[e];
    int d = ei[E + e];
    int pos = offsets[d] + atomicAdd(&cursor[d], 1);
    csr[pos] = make_int2(s, __float_as_int(dinv[s]));
  }
}

// ---------------- GEMM: C[N][128] = A[N][K] @ W[K][128] ----------------
// 32 rows/block staged in LDS; wave w handles rows w*8..w*8+7, lane l cols 2l,2l+1.
template <int K>
__global__ __launch_bounds__(256) void gemm_k(const float* __restrict__ A,
                                              const float* __restrict__ W,
                                              float* __restrict__ C, int N) {
  __shared__ float xs[32 * K];
  int t = threadIdx.x;
  long long rowBase = (long long)blockIdx.x * 32;
  const float4* Ap = (const float4*)(A + rowBase * K);
  float4* xsp = (float4*)xs;
  const int TOT = 32 * K / 4;
  for (int i = t; i < TOT; i += 256) xsp[i] = Ap[i];
  __syncthreads();

  int w = t >> 6, l = t & 63;
  int r0 = w * 8;
  int c = l * 2;
  float acc[8][2];
#pragma unroll
  for (int r = 0; r < 8; r++) acc[r][0] = acc[r][1] = 0.0f;

  for (int k = 0; k < K; k += 4) {
    float2 wr[4];
#pragma unroll
    for (int kk = 0; kk < 4; kk++) wr[kk] = *(const float2*)&W[(k + kk) * 128 + c];
#pragma unroll
    for (int r = 0; r < 8; r++) {
      float4 xv = *(const float4*)&xs[(r0 + r) * K + k];
      acc[r][0] = fmaf(xv.x, wr[0].x, acc[r][0]);
      acc[r][1] = fmaf(xv.x, wr[0].y, acc[r][1]);
      acc[r][0] = fmaf(xv.y, wr[1].x, acc[r][0]);
      acc[r][1] = fmaf(xv.y, wr[1].y, acc[r][1]);
      acc[r][0] = fmaf(xv.z, wr[2].x, acc[r][0]);
      acc[r][1] = fmaf(xv.z, wr[2].y, acc[r][1]);
      acc[r][0] = fmaf(xv.w, wr[3].x, acc[r][0]);
      acc[r][1] = fmaf(xv.w, wr[3].y, acc[r][1]);
    }
  }
#pragma unroll
  for (int r = 0; r < 8; r++) {
    *(float2*)&C[(rowBase + r0 + r) * 128 + c] = make_float2(acc[r][0], acc[r][1]);
  }
}

// ---------------- aggregation: H[n] = dinv[n]*sum_j w_j*T[src_j] + dinv^2*T[n] + b ----------------
template <bool RELU>
__global__ __launch_bounds__(256) void agg_k(const float* __restrict__ T,
                                             const float* __restrict__ dinv,
                                             const int2* __restrict__ csr,
                                             const int* __restrict__ offsets,
                                             const float* __restrict__ degf,
                                             const float* __restrict__ bias,
                                             float* __restrict__ H, int N) {
  int w = threadIdx.x >> 6, l = threadIdx.x & 63;
  int n = blockIdx.x * 4 + w;
  if (n >= N) return;
  float di = dinv[n];
  int off = offsets[n];
  int cnt = (int)degf[n] - 1;
  const float2* Tn = (const float2*)(T + (long long)n * 128);
  float2 self = Tn[l];
  float a0 = 0.0f, a1 = 0.0f;
  for (int j = 0; j < cnt; j++) {
    int2 e = csr[off + j];
    float wgt = __int_as_float(e.y);
    const float2* Ts = (const float2*)(T + (long long)e.x * 128);
    float2 v = Ts[l];
    a0 = fmaf(wgt, v.x, a0);
    a1 = fmaf(wgt, v.y, a1);
  }
  float2 b = ((const float2*)bias)[l];
  float o0 = di * a0 + di * di * self.x + b.x;
  float o1 = di * a1 + di * di * self.y + b.y;
  if (RELU) { o0 = fmaxf(o0, 0.0f); o1 = fmaxf(o1, 0.0f); }
  ((float2*)(H + (long long)n * 128))[l] = make_float2(o0, o1);
}

// ---------------- mean pool (batch is sorted) ----------------
__global__ __launch_bounds__(128) void pool_k(const float* __restrict__ H,
                                              const int* __restrict__ batch,
                                              float* __restrict__ sums,
                                              float* __restrict__ cnts, int N) {
  int f = threadIdx.x;
  int start = blockIdx.x * 512;
  int end = min(start + 512, N);
  if (start >= N) return;
  float local = 0.0f;
  int g = batch[start];
  int runStart = start;
  for (int i = start; i < end; i++) {
    int gi = batch[i];
    if (gi != g) {
      atomicAdd(&sums[g * 128 + f], local);
      if (f == 0) atomicAdd(&cnts[g], (float)(i - runStart));
      local = 0.0f;
      g = gi;
      runStart = i;
    }
    local += H[(long long)i * 128 + f];
  }
  atomicAdd(&sums[g * 128 + f], local);
  if (f == 0) atomicAdd(&cnts[g], (float)(end - runStart));
}

// ---------------- classifier: out[64][2] ----------------
__global__ __launch_bounds__(128) void final_k(const float* __restrict__ sums,
                                               const float* __restrict__ cnts,
                                               const float* __restrict__ Wc,
                                               const float* __restrict__ bc,
                                               float* __restrict__ out) {
  int t = threadIdx.x;
  int g = t >> 1, c = t & 1;
  float cg = fmaxf(cnts[g], 1.0f);
  float acc = bc[c];
  for (int f = 0; f < 128; f++) acc += (sums[g * 128 + f] / cg) * Wc[f * 2 + c];
  out[g * 2 + c] = acc;
}

extern "C" void kernel_launch(void* const* d_in, const int* in_sizes, int n_in,
                              void* d_out, int out_size, void* d_ws, size_t ws_size,
                              hipStream_t stream) {
  const float* x = (const float*)d_in[0];
  const int* ei = (const int*)d_in[1];     // [2][E] int
  const int* batch = (const int*)d_in[2];  // [N] int
  const float* W1 = (const float*)d_in[3];
  const float* b1 = (const float*)d_in[4];
  const float* W2 = (const float*)d_in[5];
  const float* b2 = (const float*)d_in[6];
  const float* W3 = (const float*)d_in[7];
  const float* b3 = (const float*)d_in[8];
  const float* Wc = (const float*)d_in[9];
  const float* bc = (const float*)d_in[10];
  float* out = (float*)d_out;

  int N = in_sizes[0] / 256;
  int E = in_sizes[1] / 2;

  char* ws = (char*)d_ws;
  size_t off = 0;
  auto alloc = [&](size_t bytes) -> void* {
    off = (off + 255) & ~(size_t)255;
    void* p = ws + off;
    off += bytes;
    return p;
  };
  float* degf = (float*)alloc((size_t)N * 4);
  float* dinv = (float*)alloc((size_t)N * 4);
  int* offsets = (int*)alloc((size_t)N * 4);
  int* cursor = (int*)alloc((size_t)N * 4);
  int* blockSums = (int*)alloc(256 * 4);
  int* blockOff = (int*)alloc(256 * 4);
  float* sums = (float*)alloc(64 * 128 * 4);
  float* cnts = (float*)alloc(64 * 4);
  int2* csr = (int2*)alloc((size_t)E * 8);
  float* bufT = (float*)alloc((size_t)N * 128 * 4);
  float* bufH = (float*)alloc((size_t)N * 128 * 4);

  int gN = (N + 255) / 256;
  int gE = (E + 255) / 256;
  int nb = (N + 1023) / 1024;

  // zero scratch that must start at 0
  hipMemsetAsync(cursor, 0, (size_t)N * 4, stream);
  hipMemsetAsync(sums, 0, 64 * 128 * 4, stream);
  hipMemsetAsync(cnts, 0, 64 * 4, stream);

  // degrees + dinv
  init_degf<<<gN, 256, 0, stream>>>(degf, N);
  deg_count<<<gE, 256, 0, stream>>>(ei + E, degf, E);
  dinv_k<<<gN, 256, 0, stream>>>(degf, dinv, N);

  // CSR offsets via scan of (deg-1)
  scan_local<<<nb, 256, 0, stream>>>(degf, offsets, blockSums, N);
  scan_block<<<1, 128, 0, stream>>>(blockSums, blockOff, nb);
  scan_add<<<gN, 256, 0, stream>>>(offsets, blockOff, N);
  fill_csr<<<gE, 256, 0, stream>>>(ei, dinv, offsets, cursor, csr, E);

  // layer 1: K=256
  gemm_k<256><<<N / 32, 256, 0, stream>>>(x, W1, bufT, N);
  agg_k<true><<<(N + 3) / 4, 256, 0, stream>>>(bufT, dinv, csr, offsets, degf, b1, bufH, N);
  // layer 2
  gemm_k<128><<<N / 32, 256, 0, stream>>>(bufH, W2, bufT, N);
  agg_k<true><<<(N + 3) / 4, 256, 0, stream>>>(bufT, dinv, csr, offsets, degf, b2, bufH, N);
  // layer 3 (no relu)
  gemm_k<128><<<N / 32, 256, 0, stream>>>(bufH, W3, bufT, N);
  agg_k<false><<<(N + 3) / 4, 256, 0, stream>>>(bufT, dinv, csr, offsets, degf, b3, bufH, N);

  // pool + classifier
  pool_k<<<(N + 511) / 512, 128, 0, stream>>>(bufH, batch, sums, cnts, N);
  final_k<<<1, 128, 0, stream>>>(sums, cnts, Wc, bc, out);
}

// Round 3
// 808.069 us; speedup vs baseline: 1.5420x; 1.5420x over previous
//
#include <hip/hip_runtime.h>
#include <hip/hip_bf16.h>

// GCN: 3x (GEMM -> normalized-adjacency aggregation) -> mean pool -> classifier.
// Aggregation is gather-only via per-call CSR (edges binned by dst).
// T (=h@W, the gathered buffer) is stored bf16 to halve gather bytes; all
// accumulation is f32. Edge loop uses lane-vectorized CSR load + __shfl
// broadcast so the per-edge gathers are independent (latency-hiding).

typedef unsigned int uint;
typedef unsigned short ushort;

__device__ inline uint bf16rne(float x) {
  uint u = __float_as_uint(x);
  return (u + 0x7FFFu + ((u >> 16) & 1u)) >> 16;
}
__device__ inline uint packbf(float a, float b) {
  return bf16rne(a) | (bf16rne(b) << 16);
}
__device__ inline float bflo(uint v) { return __uint_as_float(v << 16); }
__device__ inline float bfhi(uint v) { return __uint_as_float(v & 0xFFFF0000u); }

// ---------------- degree / dinv ----------------
__global__ __launch_bounds__(256) void init_degf(float* degf, int N) {
  int i = blockIdx.x * 256 + threadIdx.x;
  if (i < N) degf[i] = 1.0f;  // self-loop
}

__global__ __launch_bounds__(256) void deg_count(const int* __restrict__ dstIdx,
                                                 float* degf, int E) {
  int e = blockIdx.x * 256 + threadIdx.x;
  if (e < E) atomicAdd(&degf[dstIdx[e]], 1.0f);
}

__global__ __launch_bounds__(256) void dinv_k(const float* __restrict__ degf,
                                              float* __restrict__ dinv, int N) {
  int i = blockIdx.x * 256 + threadIdx.x;
  if (i < N) dinv[i] = rsqrtf(degf[i]);
}

// ---------------- exclusive scan of (deg-1) -> CSR offsets ----------------
__global__ __launch_bounds__(256) void scan_local(const float* __restrict__ degf,
                                                  int* __restrict__ offsets,
                                                  int* __restrict__ blockSums, int N) {
  __shared__ int lds[256];
  int t = threadIdx.x;
  int base = blockIdx.x * 1024 + t * 4;
  int c[4], s = 0;
#pragma unroll
  for (int i = 0; i < 4; i++) {
    int idx = base + i;
    c[i] = (idx < N) ? ((int)degf[idx] - 1) : 0;
    s += c[i];
  }
  lds[t] = s;
  __syncthreads();
  for (int d = 1; d < 256; d <<= 1) {
    int add = (t >= d) ? lds[t - d] : 0;
    __syncthreads();
    lds[t] += add;
    __syncthreads();
  }
  int incl = lds[t];
  int run = incl - s;
#pragma unroll
  for (int i = 0; i < 4; i++) {
    int idx = base + i;
    if (idx < N) offsets[idx] = run;
    run += c[i];
  }
  if (t == 255) blockSums[blockIdx.x] = incl;
}

__global__ __launch_bounds__(128) void scan_block(const int* __restrict__ blockSums,
                                                  int* __restrict__ blockOff, int nb) {
  __shared__ int lds[128];
  int t = threadIdx.x;
  int v = (t < nb) ? blockSums[t] : 0;
  lds[t] = v;
  __syncthreads();
  for (int d = 1; d < 128; d <<= 1) {
    int add = (t >= d) ? lds[t - d] : 0;
    __syncthreads();
    lds[t] += add;
    __syncthreads();
  }
  blockOff[t] = lds[t] - v;
}

__global__ __launch_bounds__(256) void scan_add(int* __restrict__ offsets,
                                                const int* __restrict__ blockOff, int N) {
  int i = blockIdx.x * 256 + threadIdx.x;
  if (i < N) offsets[i] += blockOff[i >> 10];
}

// ---------------- CSR fill: csr[pos] = {src, dinv[src]} ----------------
__global__ __launch_bounds__(256) void fill_csr(const int* __restrict__ ei,
                                                const float* __restrict__ dinv,
                                                const int* __restrict__ offsets,
                                                int* __restrict__ cursor,
                                                int2* __restrict__ csr, int E) {
  int e = blockIdx.x * 256 + threadIdx.x;
  if (e < E) {
    int s = ei[e];
    int d = ei[E + e];
    int pos = offsets[d] + atomicAdd(&cursor[d], 1);
    csr[pos] = make_int2(s, __float_as_int(dinv[s]));
  }
}

// ---------------- GEMM: T[N][128] = A[N][K] @ W[K][128], T in bf16 ----------------
// 32 rows/block staged in LDS; wave w rows w*8..w*8+7, lane l cols 2l,2l+1.
template <int K>
__global__ __launch_bounds__(256) void gemm_k(const float* __restrict__ A,
                                              const float* __restrict__ W,
                                              ushort* __restrict__ C, int N) {
  __shared__ float xs[32 * K];
  int t = threadIdx.x;
  long long rowBase = (long long)blockIdx.x * 32;
  const float4* Ap = (const float4*)(A + rowBase * K);
  float4* xsp = (float4*)xs;
  const int TOT = 32 * K / 4;
  for (int i = t; i < TOT; i += 256) xsp[i] = Ap[i];
  __syncthreads();

  int w = t >> 6, l = t & 63;
  int r0 = w * 8;
  int c = l * 2;
  float acc[8][2];
#pragma unroll
  for (int r = 0; r < 8; r++) acc[r][0] = acc[r][1] = 0.0f;

  for (int k = 0; k < K; k += 4) {
    float2 wr[4];
#pragma unroll
    for (int kk = 0; kk < 4; kk++) wr[kk] = *(const float2*)&W[(k + kk) * 128 + c];
#pragma unroll
    for (int r = 0; r < 8; r++) {
      float4 xv = *(const float4*)&xs[(r0 + r) * K + k];
      acc[r][0] = fmaf(xv.x, wr[0].x, acc[r][0]);
      acc[r][1] = fmaf(xv.x, wr[0].y, acc[r][1]);
      acc[r][0] = fmaf(xv.y, wr[1].x, acc[r][0]);
      acc[r][1] = fmaf(xv.y, wr[1].y, acc[r][1]);
      acc[r][0] = fmaf(xv.z, wr[2].x, acc[r][0]);
      acc[r][1] = fmaf(xv.z, wr[2].y, acc[r][1]);
      acc[r][0] = fmaf(xv.w, wr[3].x, acc[r][0]);
      acc[r][1] = fmaf(xv.w, wr[3].y, acc[r][1]);
    }
  }
#pragma unroll
  for (int r = 0; r < 8; r++) {
    uint* Crow = (uint*)(C + (rowBase + r0 + r) * 128);
    Crow[l] = packbf(acc[r][0], acc[r][1]);
  }
}

// ---------------- aggregation ----------------
// H[n] = dinv[n]*sum_j w_j*T[src_j] + dinv[n]^2*T[n] + b ; T bf16, H f32.
// One wave per node; CSR entries vector-loaded across lanes, broadcast via shfl,
// gathers unrolled x4 for memory-level parallelism.
template <bool RELU>
__global__ __launch_bounds__(256) void agg_k(const ushort* __restrict__ T,
                                             const float* __restrict__ dinv,
                                             const int2* __restrict__ csr,
                                             const int* __restrict__ offsets,
                                             const float* __restrict__ degf,
                                             const float* __restrict__ bias,
                                             float* __restrict__ H, int N) {
  int w = threadIdx.x >> 6, l = threadIdx.x & 63;
  int n = blockIdx.x * 4 + w;
  if (n >= N) return;
  float di = dinv[n];
  int off = offsets[n];
  int cnt = (int)degf[n] - 1;
  const uint* Tn = (const uint*)(T + (size_t)n * 128);
  uint selfv = Tn[l];
  float a0 = 0.0f, a1 = 0.0f;

  for (int j0 = 0; j0 < cnt; j0 += 64) {
    int idx = j0 + l;
    int2 e = (idx < cnt) ? csr[off + idx] : make_int2(0, 0);
    int ex = e.x;
    float ew = __int_as_float(e.y);
    int m = min(cnt - j0, 64);
    int j = 0;
    for (; j + 4 <= m; j += 4) {
      int r0 = __shfl(ex, j), r1 = __shfl(ex, j + 1);
      int r2 = __shfl(ex, j + 2), r3 = __shfl(ex, j + 3);
      float w0 = __shfl(ew, j), w1 = __shfl(ew, j + 1);
      float w2 = __shfl(ew, j + 2), w3 = __shfl(ew, j + 3);
      uint v0 = ((const uint*)(T + (size_t)r0 * 128))[l];
      uint v1 = ((const uint*)(T + (size_t)r1 * 128))[l];
      uint v2 = ((const uint*)(T + (size_t)r2 * 128))[l];
      uint v3 = ((const uint*)(T + (size_t)r3 * 128))[l];
      a0 = fmaf(w0, bflo(v0), a0); a1 = fmaf(w0, bfhi(v0), a1);
      a0 = fmaf(w1, bflo(v1), a0); a1 = fmaf(w1, bfhi(v1), a1);
      a0 = fmaf(w2, bflo(v2), a0); a1 = fmaf(w2, bfhi(v2), a1);
      a0 = fmaf(w3, bflo(v3), a0); a1 = fmaf(w3, bfhi(v3), a1);
    }
    for (; j < m; j++) {
      int r = __shfl(ex, j);
      float wj = __shfl(ew, j);
      uint v = ((const uint*)(T + (size_t)r * 128))[l];
      a0 = fmaf(wj, bflo(v), a0);
      a1 = fmaf(wj, bfhi(v), a1);
    }
  }

  float2 b = ((const float2*)bias)[l];
  float o0 = di * a0 + di * di * bflo(selfv) + b.x;
  float o1 = di * a1 + di * di * bfhi(selfv) + b.y;
  if (RELU) { o0 = fmaxf(o0, 0.0f); o1 = fmaxf(o1, 0.0f); }
  ((float2*)(H + (size_t)n * 128))[l] = make_float2(o0, o1);
}

// ---------------- per-graph boundaries (batch sorted) ----------------
__global__ __launch_bounds__(256) void boundary_k(const int* __restrict__ batch,
                                                  int* __restrict__ gstart,
                                                  int* __restrict__ gend, int N) {
  int i = blockIdx.x * 256 + threadIdx.x;
  if (i >= N) return;
  int b = batch[i];
  if (i == 0 || batch[i - 1] != b) gstart[b] = i;
  if (i == N - 1 || batch[i + 1] != b) gend[b] = i + 1;
}

// ---------------- mean pool: 8 splits per graph ----------------
__global__ __launch_bounds__(128) void pool_k(const float* __restrict__ H,
                                              const int* __restrict__ gstart,
                                              const int* __restrict__ gend,
                                              float* __restrict__ sums) {
  int g = blockIdx.x >> 3, s = blockIdx.x & 7;
  int gs = gstart[g], ge = gend[g];
  int len = ge - gs;
  if (len <= 0) return;
  int chunk = (len + 7) >> 3;
  int r0 = gs + s * chunk;
  int r1 = min(r0 + chunk, ge);
  if (r0 >= r1) return;
  int f = threadIdx.x;
  float local = 0.0f;
  int r = r0;
  for (; r + 4 <= r1; r += 4) {
    float h0 = H[(size_t)r * 128 + f];
    float h1 = H[(size_t)(r + 1) * 128 + f];
    float h2 = H[(size_t)(r + 2) * 128 + f];
    float h3 = H[(size_t)(r + 3) * 128 + f];
    local += (h0 + h1) + (h2 + h3);
  }
  for (; r < r1; r++) local += H[(size_t)r * 128 + f];
  atomicAdd(&sums[g * 128 + f], local);
}

// ---------------- classifier: out[64][2] ----------------
__global__ __launch_bounds__(128) void final_k(const float* __restrict__ sums,
                                               const int* __restrict__ gstart,
                                               const int* __restrict__ gend,
                                               const float* __restrict__ Wc,
                                               const float* __restrict__ bc,
                                               float* __restrict__ out) {
  int t = threadIdx.x;
  int g = t >> 1, c = t & 1;
  float cg = fmaxf((float)(gend[g] - gstart[g]), 1.0f);
  float acc = bc[c];
  for (int f = 0; f < 128; f++) acc += (sums[g * 128 + f] / cg) * Wc[f * 2 + c];
  out[g * 2 + c] = acc;
}

extern "C" void kernel_launch(void* const* d_in, const int* in_sizes, int n_in,
                              void* d_out, int out_size, void* d_ws, size_t ws_size,
                              hipStream_t stream) {
  const float* x = (const float*)d_in[0];
  const int* ei = (const int*)d_in[1];     // [2][E]
  const int* batch = (const int*)d_in[2];  // [N]
  const float* W1 = (const float*)d_in[3];
  const float* b1 = (const float*)d_in[4];
  const float* W2 = (const float*)d_in[5];
  const float* b2 = (const float*)d_in[6];
  const float* W3 = (const float*)d_in[7];
  const float* b3 = (const float*)d_in[8];
  const float* Wc = (const float*)d_in[9];
  const float* bc = (const float*)d_in[10];
  float* out = (float*)d_out;

  int N = in_sizes[0] / 256;
  int E = in_sizes[1] / 2;

  char* ws = (char*)d_ws;
  size_t off = 0;
  auto alloc = [&](size_t bytes) -> void* {
    off = (off + 255) & ~(size_t)255;
    void* p = ws + off;
    off += bytes;
    return p;
  };
  float* degf = (float*)alloc((size_t)N * 4);
  float* dinv = (float*)alloc((size_t)N * 4);
  int* offsets = (int*)alloc((size_t)N * 4);
  int* cursor = (int*)alloc((size_t)N * 4);
  int* blockSums = (int*)alloc(256 * 4);
  int* blockOff = (int*)alloc(256 * 4);
  float* sums = (float*)alloc(64 * 128 * 4);
  int* gstart = (int*)alloc(64 * 4);
  int* gend = (int*)alloc(64 * 4);
  int2* csr = (int2*)alloc((size_t)E * 8);
  ushort* bufT = (ushort*)alloc((size_t)N * 128 * 2);  // bf16
  float* bufH = (float*)alloc((size_t)N * 128 * 4);

  int gN = (N + 255) / 256;
  int gE = (E + 255) / 256;
  int nb = (N + 1023) / 1024;

  hipMemsetAsync(cursor, 0, (size_t)N * 4, stream);
  hipMemsetAsync(sums, 0, 64 * 128 * 4, stream);
  hipMemsetAsync(gstart, 0, 64 * 4, stream);
  hipMemsetAsync(gend, 0, 64 * 4, stream);

  // degrees + dinv
  init_degf<<<gN, 256, 0, stream>>>(degf, N);
  deg_count<<<gE, 256, 0, stream>>>(ei + E, degf, E);
  dinv_k<<<gN, 256, 0, stream>>>(degf, dinv, N);

  // CSR
  scan_local<<<nb, 256, 0, stream>>>(degf, offsets, blockSums, N);
  scan_block<<<1, 128, 0, stream>>>(blockSums, blockOff, nb);
  scan_add<<<gN, 256, 0, stream>>>(offsets, blockOff, N);
  fill_csr<<<gE, 256, 0, stream>>>(ei, dinv, offsets, cursor, csr, E);

  // graph boundaries (independent)
  boundary_k<<<gN, 256, 0, stream>>>(batch, gstart, gend, N);

  // layer 1
  gemm_k<256><<<N / 32, 256, 0, stream>>>(x, W1, bufT, N);
  agg_k<true><<<(N + 3) / 4, 256, 0, stream>>>(bufT, dinv, csr, offsets, degf, b1, bufH, N);
  // layer 2
  gemm_k<128><<<N / 32, 256, 0, stream>>>(bufH, W2, bufT, N);
  agg_k<true><<<(N + 3) / 4, 256, 0, stream>>>(bufT, dinv, csr, offsets, degf, b2, bufH, N);
  // layer 3
  gemm_k<128><<<N / 32, 256, 0, stream>>>(bufH, W3, bufT, N);
  agg_k<false><<<(N + 3) / 4, 256, 0, stream>>>(bufT, dinv, csr, offsets, degf, b3, bufH, N);

  // pool + classifier
  pool_k<<<64 * 8, 128, 0, stream>>>(bufH, gstart, gend, sums);
  final_k<<<1, 128, 0, stream>>>(sums, gstart, gend, Wc, bc, out);
}

// Round 5
// 693.109 us; speedup vs baseline: 1.7977x; 1.1659x over previous
//
#include <hip/hip_runtime.h>
#include <hip/hip_bf16.h>

// GCN: 3x (MFMA-bf16 GEMM -> CSR gather aggregation) -> mean pool -> classifier.
// All hidden state bf16 (f32 accumulate everywhere); errors wash out in pooling.

typedef unsigned int uint;
typedef unsigned short ushort;
typedef __bf16 bf16x8 __attribute__((ext_vector_type(8)));
typedef float f32x4 __attribute__((ext_vector_type(4)));

__device__ inline uint bf16rne(float x) {
  uint u = __float_as_uint(x);
  return (u + 0x7FFFu + ((u >> 16) & 1u)) >> 16;
}
__device__ inline uint packbf(float a, float b) {
  return bf16rne(a) | (bf16rne(b) << 16);
}
__device__ inline float bflo(uint v) { return __uint_as_float(v << 16); }
__device__ inline float bfhi(uint v) { return __uint_as_float(v & 0xFFFF0000u); }

// ---------------- degree / dinv ----------------
__global__ __launch_bounds__(256) void init_degf(float* degf, int N) {
  int i = blockIdx.x * 256 + threadIdx.x;
  if (i < N) degf[i] = 1.0f;  // self-loop
}

__global__ __launch_bounds__(256) void deg_count(const int* __restrict__ dstIdx,
                                                 float* degf, int E) {
  int e = blockIdx.x * 256 + threadIdx.x;
  if (e < E) atomicAdd(&degf[dstIdx[e]], 1.0f);
}

__global__ __launch_bounds__(256) void dinv_k(const float* __restrict__ degf,
                                              float* __restrict__ dinv, int N) {
  int i = blockIdx.x * 256 + threadIdx.x;
  if (i < N) dinv[i] = rsqrtf(degf[i]);
}

// ---------------- exclusive scan of (deg-1) -> CSR offsets ----------------
__global__ __launch_bounds__(256) void scan_local(const float* __restrict__ degf,
                                                  int* __restrict__ offsets,
                                                  int* __restrict__ blockSums, int N) {
  __shared__ int lds[256];
  int t = threadIdx.x;
  int base = blockIdx.x * 1024 + t * 4;
  int c[4], s = 0;
#pragma unroll
  for (int i = 0; i < 4; i++) {
    int idx = base + i;
    c[i] = (idx < N) ? ((int)degf[idx] - 1) : 0;
    s += c[i];
  }
  lds[t] = s;
  __syncthreads();
  for (int d = 1; d < 256; d <<= 1) {
    int add = (t >= d) ? lds[t - d] : 0;
    __syncthreads();
    lds[t] += add;
    __syncthreads();
  }
  int incl = lds[t];
  int run = incl - s;
#pragma unroll
  for (int i = 0; i < 4; i++) {
    int idx = base + i;
    if (idx < N) offsets[idx] = run;
    run += c[i];
  }
  if (t == 255) blockSums[blockIdx.x] = incl;
}

__global__ __launch_bounds__(128) void scan_block(const int* __restrict__ blockSums,
                                                  int* __restrict__ blockOff, int nb) {
  __shared__ int lds[128];
  int t = threadIdx.x;
  int v = (t < nb) ? blockSums[t] : 0;
  lds[t] = v;
  __syncthreads();
  for (int d = 1; d < 128; d <<= 1) {
    int add = (t >= d) ? lds[t - d] : 0;
    __syncthreads();
    lds[t] += add;
    __syncthreads();
  }
  blockOff[t] = lds[t] - v;
}

__global__ __launch_bounds__(256) void scan_add(int* __restrict__ offsets,
                                                const int* __restrict__ blockOff, int N) {
  int i = blockIdx.x * 256 + threadIdx.x;
  if (i < N) offsets[i] += blockOff[i >> 10];
}

// ---------------- CSR fill: csr[pos] = {src, dinv[src]} ----------------
__global__ __launch_bounds__(256) void fill_csr(const int* __restrict__ ei,
                                                const float* __restrict__ dinv,
                                                const int* __restrict__ offsets,
                                                int* __restrict__ cursor,
                                                int2* __restrict__ csr, int E) {
  int e = blockIdx.x * 256 + threadIdx.x;
  if (e < E) {
    int s = ei[e];
    int d = ei[E + e];
    int pos = offsets[d] + atomicAdd(&cursor[d], 1);
    csr[pos] = make_int2(s, __float_as_int(dinv[s]));
  }
}

// ---------------- W -> W^T bf16 ----------------
__global__ __launch_bounds__(256) void wt_k(const float* __restrict__ W,
                                            ushort* __restrict__ WT, int K) {
  int idx = blockIdx.x * 256 + threadIdx.x;
  if (idx >= K * 128) return;
  int k = idx >> 7, c = idx & 127;
  WT[c * K + k] = (ushort)bf16rne(W[idx]);
}

// ---------------- MFMA GEMM: C[N][128] = A[N][K] @ W[K][128], bf16 ----------------
// 128 threads = 2 waves; wave wv owns rows blk*32 + wv*16 .. +15, all 128 cols.
// A fragments: lane l -> row=(l&15), k=(l>>4)*8+j (16B contiguous).
// B fragments from WT[col][k]: col=(l&15), same k slice.
// D: col=(l&15), row=(l>>4)*4+reg.
template <int K, bool AF32>
__global__ __launch_bounds__(128) void mgemm_k(const void* __restrict__ Ain,
                                               const ushort* __restrict__ WT,
                                               ushort* __restrict__ C, int N) {
  constexpr int KT = K / 32;
  int t = threadIdx.x;
  int wv = t >> 6, l = t & 63;
  int row16 = blockIdx.x * 32 + wv * 16;
  size_t rA = (size_t)(row16 + (l & 15)) * K;
  int koff = (l >> 4) * 8;

  bf16x8 a[KT];
  if (AF32) {
    const float* A = (const float*)Ain;
#pragma unroll
    for (int kt = 0; kt < KT; kt++) {
      const float4* p = (const float4*)(A + rA + kt * 32 + koff);
      float4 lo = p[0], hi = p[1];
      bf16x8 av;
      av[0] = (__bf16)lo.x; av[1] = (__bf16)lo.y; av[2] = (__bf16)lo.z; av[3] = (__bf16)lo.w;
      av[4] = (__bf16)hi.x; av[5] = (__bf16)hi.y; av[6] = (__bf16)hi.z; av[7] = (__bf16)hi.w;
      a[kt] = av;
    }
  } else {
    const ushort* A = (const ushort*)Ain;
#pragma unroll
    for (int kt = 0; kt < KT; kt++) a[kt] = *(const bf16x8*)(A + rA + kt * 32 + koff);
  }

  f32x4 acc[8];
#pragma unroll
  for (int ct = 0; ct < 8; ct++) { f32x4 z = {0.f, 0.f, 0.f, 0.f}; acc[ct] = z; }

  const ushort* WTl = WT + (size_t)(l & 15) * K + koff;
#pragma unroll
  for (int kt = 0; kt < KT; kt++) {
#pragma unroll
    for (int ct = 0; ct < 8; ct++) {
      bf16x8 b = *(const bf16x8*)(WTl + (size_t)ct * 16 * K + kt * 32);
      acc[ct] = __builtin_amdgcn_mfma_f32_16x16x32_bf16(a[kt], b, acc[ct], 0, 0, 0);
    }
  }

  int rowD = row16 + (l >> 4) * 4;
  int colD = l & 15;
  __bf16* Cb = (__bf16*)C;
#pragma unroll
  for (int ct = 0; ct < 8; ct++) {
#pragma unroll
    for (int r = 0; r < 4; r++) {
      Cb[(size_t)(rowD + r) * 128 + ct * 16 + colD] = (__bf16)acc[ct][r];
    }
  }
}

// ---------------- aggregation ----------------
// H[n] = dinv[n]*sum_j w_j*T[src_j] + dinv[n]^2*T[n] + b ; T bf16, acc f32.
template <bool RELU, bool OUTBF>
__global__ __launch_bounds__(256) void agg_k(const ushort* __restrict__ T,
                                             const float* __restrict__ dinv,
                                             const int2* __restrict__ csr,
                                             const int* __restrict__ offsets,
                                             const float* __restrict__ degf,
                                             const float* __restrict__ bias,
                                             void* __restrict__ Hout, int N) {
  int w = threadIdx.x >> 6, l = threadIdx.x & 63;
  int n = blockIdx.x * 4 + w;
  if (n >= N) return;
  float di = dinv[n];
  int off = offsets[n];
  int cnt = (int)degf[n] - 1;
  const uint* Tn = (const uint*)(T + (size_t)n * 128);
  uint selfv = Tn[l];
  float a0 = 0.0f, a1 = 0.0f;

  for (int j0 = 0; j0 < cnt; j0 += 64) {
    int idx = j0 + l;
    int2 e = (idx < cnt) ? csr[off + idx] : make_int2(0, 0);
    int ex = e.x;
    float ew = __int_as_float(e.y);
    int m = min(cnt - j0, 64);
    int j = 0;
    for (; j + 4 <= m; j += 4) {
      int r0 = __shfl(ex, j), r1 = __shfl(ex, j + 1);
      int r2 = __shfl(ex, j + 2), r3 = __shfl(ex, j + 3);
      float w0 = __shfl(ew, j), w1 = __shfl(ew, j + 1);
      float w2 = __shfl(ew, j + 2), w3 = __shfl(ew, j + 3);
      uint v0 = ((const uint*)(T + (size_t)r0 * 128))[l];
      uint v1 = ((const uint*)(T + (size_t)r1 * 128))[l];
      uint v2 = ((const uint*)(T + (size_t)r2 * 128))[l];
      uint v3 = ((const uint*)(T + (size_t)r3 * 128))[l];
      a0 = fmaf(w0, bflo(v0), a0); a1 = fmaf(w0, bfhi(v0), a1);
      a0 = fmaf(w1, bflo(v1), a0); a1 = fmaf(w1, bfhi(v1), a1);
      a0 = fmaf(w2, bflo(v2), a0); a1 = fmaf(w2, bfhi(v2), a1);
      a0 = fmaf(w3, bflo(v3), a0); a1 = fmaf(w3, bfhi(v3), a1);
    }
    for (; j < m; j++) {
      int r = __shfl(ex, j);
      float wj = __shfl(ew, j);
      uint v = ((const uint*)(T + (size_t)r * 128))[l];
      a0 = fmaf(wj, bflo(v), a0);
      a1 = fmaf(wj, bfhi(v), a1);
    }
  }

  float2 b = ((const float2*)bias)[l];
  float o0 = di * a0 + di * di * bflo(selfv) + b.x;
  float o1 = di * a1 + di * di * bfhi(selfv) + b.y;
  if (RELU) { o0 = fmaxf(o0, 0.0f); o1 = fmaxf(o1, 0.0f); }
  if (OUTBF) {
    ((uint*)Hout)[(size_t)n * 64 + l] = packbf(o0, o1);
  } else {
    ((float2*)Hout)[(size_t)n * 64 + l] = make_float2(o0, o1);
  }
}

// ---------------- per-graph boundaries (batch sorted) ----------------
__global__ __launch_bounds__(256) void boundary_k(const int* __restrict__ batch,
                                                  int* __restrict__ gstart,
                                                  int* __restrict__ gend, int N) {
  int i = blockIdx.x * 256 + threadIdx.x;
  if (i >= N) return;
  int b = batch[i];
  if (i == 0 || batch[i - 1] != b) gstart[b] = i;
  if (i == N - 1 || batch[i + 1] != b) gend[b] = i + 1;
}

// ---------------- mean pool: 8 splits per graph ----------------
__global__ __launch_bounds__(128) void pool_k(const float* __restrict__ H,
                                              const int* __restrict__ gstart,
                                              const int* __restrict__ gend,
                                              float* __restrict__ sums) {
  int g = blockIdx.x >> 3, s = blockIdx.x & 7;
  int gs = gstart[g], ge = gend[g];
  int len = ge - gs;
  if (len <= 0) return;
  int chunk = (len + 7) >> 3;
  int r0 = gs + s * chunk;
  int r1 = min(r0 + chunk, ge);
  if (r0 >= r1) return;
  int f = threadIdx.x;
  float local = 0.0f;
  int r = r0;
  for (; r + 4 <= r1; r += 4) {
    float h0 = H[(size_t)r * 128 + f];
    float h1 = H[(size_t)(r + 1) * 128 + f];
    float h2 = H[(size_t)(r + 2) * 128 + f];
    float h3 = H[(size_t)(r + 3) * 128 + f];
    local += (h0 + h1) + (h2 + h3);
  }
  for (; r < r1; r++) local += H[(size_t)r * 128 + f];
  atomicAdd(&sums[g * 128 + f], local);
}

// ---------------- classifier: out[64][2] ----------------
__global__ __launch_bounds__(128) void final_k(const float* __restrict__ sums,
                                               const int* __restrict__ gstart,
                                               const int* __restrict__ gend,
                                               const float* __restrict__ Wc,
                                               const float* __restrict__ bc,
                                               float* __restrict__ out) {
  int t = threadIdx.x;
  int g = t >> 1, c = t & 1;
  float cg = fmaxf((float)(gend[g] - gstart[g]), 1.0f);
  float acc = bc[c];
  for (int f = 0; f < 128; f++) acc += (sums[g * 128 + f] / cg) * Wc[f * 2 + c];
  out[g * 2 + c] = acc;
}

extern "C" void kernel_launch(void* const* d_in, const int* in_sizes, int n_in,
                              void* d_out, int out_size, void* d_ws, size_t ws_size,
                              hipStream_t stream) {
  const float* x = (const float*)d_in[0];
  const int* ei = (const int*)d_in[1];     // [2][E]
  const int* batch = (const int*)d_in[2];  // [N]
  const float* W1 = (const float*)d_in[3];
  const float* b1 = (const float*)d_in[4];
  const float* W2 = (const float*)d_in[5];
  const float* b2 = (const float*)d_in[6];
  const float* W3 = (const float*)d_in[7];
  const float* b3 = (const float*)d_in[8];
  const float* Wc = (const float*)d_in[9];
  const float* bc = (const float*)d_in[10];
  float* out = (float*)d_out;

  int N = in_sizes[0] / 256;
  int E = in_sizes[1] / 2;

  char* ws = (char*)d_ws;
  size_t off = 0;
  auto alloc = [&](size_t bytes) -> void* {
    off = (off + 255) & ~(size_t)255;
    void* p = ws + off;
    off += bytes;
    return p;
  };
  float* degf = (float*)alloc((size_t)N * 4);
  float* dinv = (float*)alloc((size_t)N * 4);
  int* offsets = (int*)alloc((size_t)N * 4);
  int* cursor = (int*)alloc((size_t)N * 4);
  int* blockSums = (int*)alloc(256 * 4);
  int* blockOff = (int*)alloc(256 * 4);
  float* sums = (float*)alloc(64 * 128 * 4);
  int* gstart = (int*)alloc(64 * 4);
  int* gend = (int*)alloc(64 * 4);
  ushort* WT1 = (ushort*)alloc(256 * 128 * 2);
  ushort* WT2 = (ushort*)alloc(128 * 128 * 2);
  ushort* WT3 = (ushort*)alloc(128 * 128 * 2);
  int2* csr = (int2*)alloc((size_t)E * 8);
  ushort* bufT = (ushort*)alloc((size_t)N * 128 * 2);   // GEMM out (bf16)
  ushort* bufHb = (ushort*)alloc((size_t)N * 128 * 2);  // agg out layers 1-2 (bf16)
  float* bufH = (float*)alloc((size_t)N * 128 * 4);     // agg out layer 3 (f32)

  int gN = (N + 255) / 256;
  int gE = (E + 255) / 256;
  int nb = (N + 1023) / 1024;

  hipMemsetAsync(cursor, 0, (size_t)N * 4, stream);
  hipMemsetAsync(sums, 0, 64 * 128 * 4, stream);
  hipMemsetAsync(gstart, 0, 64 * 4, stream);
  hipMemsetAsync(gend, 0, 64 * 4, stream);

  // degrees + dinv
  init_degf<<<gN, 256, 0, stream>>>(degf, N);
  deg_count<<<gE, 256, 0, stream>>>(ei + E, degf, E);
  dinv_k<<<gN, 256, 0, stream>>>(degf, dinv, N);

  // CSR
  scan_local<<<nb, 256, 0, stream>>>(degf, offsets, blockSums, N);
  scan_block<<<1, 128, 0, stream>>>(blockSums, blockOff, nb);
  scan_add<<<gN, 256, 0, stream>>>(offsets, blockOff, N);
  fill_csr<<<gE, 256, 0, stream>>>(ei, dinv, offsets, cursor, csr, E);

  // graph boundaries + W transposes
  boundary_k<<<gN, 256, 0, stream>>>(batch, gstart, gend, N);
  wt_k<<<(256 * 128 + 255) / 256, 256, 0, stream>>>(W1, WT1, 256);
  wt_k<<<(128 * 128 + 255) / 256, 256, 0, stream>>>(W2, WT2, 128);
  wt_k<<<(128 * 128 + 255) / 256, 256, 0, stream>>>(W3, WT3, 128);

  // layer 1 (A = x, f32 -> bf16 fused)
  mgemm_k<256, true><<<N / 32, 128, 0, stream>>>(x, WT1, bufT, N);
  agg_k<true, true><<<(N + 3) / 4, 256, 0, stream>>>(bufT, dinv, csr, offsets, degf, b1, bufHb, N);
  // layer 2
  mgemm_k<128, false><<<N / 32, 128, 0, stream>>>(bufHb, WT2, bufT, N);
  agg_k<true, true><<<(N + 3) / 4, 256, 0, stream>>>(bufT, dinv, csr, offsets, degf, b2, bufHb, N);
  // layer 3
  mgemm_k<128, false><<<N / 32, 128, 0, stream>>>(bufHb, WT3, bufT, N);
  agg_k<false, false><<<(N + 3) / 4, 256, 0, stream>>>(bufT, dinv, csr, offsets, degf, b3, bufH, N);

  // pool + classifier
  pool_k<<<64 * 8, 128, 0, stream>>>(bufH, gstart, gend, sums);
  final_k<<<1, 128, 0, stream>>>(sums, gstart, gend, Wc, bc, out);
}

// Round 6
// 638.889 us; speedup vs baseline: 1.9503x; 1.0849x over previous
//
#include <hip/hip_runtime.h>
#include <hip/hip_bf16.h>

// GCN: 3x (MFMA-bf16 GEMM w/ LDS-staged pre-permuted B -> CSR gather agg)
// -> mean pool -> classifier. Hidden state bf16, f32 accumulate.

typedef unsigned int uint;
typedef unsigned short ushort;
typedef __bf16 bf16x8 __attribute__((ext_vector_type(8)));
typedef float f32x4 __attribute__((ext_vector_type(4)));

__device__ inline uint bf16rne(float x) {
  uint u = __float_as_uint(x);
  return (u + 0x7FFFu + ((u >> 16) & 1u)) >> 16;
}
__device__ inline uint packbf(float a, float b) {
  return bf16rne(a) | (bf16rne(b) << 16);
}
__device__ inline float bflo(uint v) { return __uint_as_float(v << 16); }
__device__ inline float bfhi(uint v) { return __uint_as_float(v & 0xFFFF0000u); }

// ---------------- degree / dinv ----------------
__global__ __launch_bounds__(256) void init_degf(float* degf, int N) {
  int i = blockIdx.x * 256 + threadIdx.x;
  if (i < N) degf[i] = 1.0f;  // self-loop
}

__global__ __launch_bounds__(256) void deg_count(const int* __restrict__ dstIdx,
                                                 float* degf, int E) {
  int e = blockIdx.x * 256 + threadIdx.x;
  if (e < E) atomicAdd(&degf[dstIdx[e]], 1.0f);
}

__global__ __launch_bounds__(256) void dinv_k(const float* __restrict__ degf,
                                              float* __restrict__ dinv, int N) {
  int i = blockIdx.x * 256 + threadIdx.x;
  if (i < N) dinv[i] = rsqrtf(degf[i]);
}

// ---------------- exclusive scan of (deg-1) -> CSR offsets ----------------
__global__ __launch_bounds__(256) void scan_local(const float* __restrict__ degf,
                                                  int* __restrict__ offsets,
                                                  int* __restrict__ blockSums, int N) {
  __shared__ int lds[256];
  int t = threadIdx.x;
  int base = blockIdx.x * 1024 + t * 4;
  int c[4], s = 0;
#pragma unroll
  for (int i = 0; i < 4; i++) {
    int idx = base + i;
    c[i] = (idx < N) ? ((int)degf[idx] - 1) : 0;
    s += c[i];
  }
  lds[t] = s;
  __syncthreads();
  for (int d = 1; d < 256; d <<= 1) {
    int add = (t >= d) ? lds[t - d] : 0;
    __syncthreads();
    lds[t] += add;
    __syncthreads();
  }
  int incl = lds[t];
  int run = incl - s;
#pragma unroll
  for (int i = 0; i < 4; i++) {
    int idx = base + i;
    if (idx < N) offsets[idx] = run;
    run += c[i];
  }
  if (t == 255) blockSums[blockIdx.x] = incl;
}

__global__ __launch_bounds__(128) void scan_block(const int* __restrict__ blockSums,
                                                  int* __restrict__ blockOff, int nb) {
  __shared__ int lds[128];
  int t = threadIdx.x;
  int v = (t < nb) ? blockSums[t] : 0;
  lds[t] = v;
  __syncthreads();
  for (int d = 1; d < 128; d <<= 1) {
    int add = (t >= d) ? lds[t - d] : 0;
    __syncthreads();
    lds[t] += add;
    __syncthreads();
  }
  blockOff[t] = lds[t] - v;
}

__global__ __launch_bounds__(256) void scan_add(int* __restrict__ offsets,
                                                const int* __restrict__ blockOff, int N) {
  int i = blockIdx.x * 256 + threadIdx.x;
  if (i < N) offsets[i] += blockOff[i >> 10];
}

// ---------------- CSR fill: csr[pos] = {src, dinv[src]} ----------------
// cursor pre-seeded with offsets (d2d copy), so atomicAdd yields absolute slot.
__global__ __launch_bounds__(256) void fill_csr(const int* __restrict__ ei,
                                                const float* __restrict__ dinv,
                                                int* __restrict__ cursor,
                                                int2* __restrict__ csr, int E) {
  int e = blockIdx.x * 256 + threadIdx.x;
  if (e < E) {
    int s = ei[e];
    int d = ei[E + e];
    int pos = atomicAdd(&cursor[d], 1);
    csr[pos] = make_int2(s, __float_as_int(dinv[s]));
  }
}

// ---------------- W -> permuted fragment-ordered bf16 ----------------
// WTp element o = ((ct*KT+kt)*64 + l)*8 + j  holds  W[(kt*32+(l>>4)*8+j)*128 + ct*16+(l&15)]
__global__ __launch_bounds__(256) void wtp_k(const float* __restrict__ W,
                                             ushort* __restrict__ WTp, int K, int KT) {
  int idx = blockIdx.x * 256 + threadIdx.x;
  if (idx >= K * 128) return;
  int j = idx & 7;
  int l = (idx >> 3) & 63;
  int f = idx >> 9;
  int kt = f % KT, ct = f / KT;
  int k = kt * 32 + (l >> 4) * 8 + j;
  int c = ct * 16 + (l & 15);
  WTp[idx] = (ushort)bf16rne(W[k * 128 + c]);
}

// ---------------- MFMA GEMM: C[N][128] = A[N][K] @ W[K][128], bf16 ----------------
// 256 threads = 4 waves; BM=128 rows/block; wave wv rows wv*32..+31 (2 m-frags).
// B staged in LDS in fragment order: ds_read_b128 at lane*16, conflict-free.
template <int K, bool AF32>
__global__ __launch_bounds__(256) void mgemm_k(const void* __restrict__ Ain,
                                               const ushort* __restrict__ WTp,
                                               ushort* __restrict__ C, int N) {
  constexpr int KT = K / 32;
  __shared__ ushort bs[K * 128];

  int t = threadIdx.x;
  // stage permuted B: straight coalesced copy
  {
    const uint4* src = (const uint4*)WTp;
    uint4* dst = (uint4*)bs;
    const int NCHUNK = K * 128 / 8;
#pragma unroll
    for (int i = t; i < NCHUNK; i += 256) dst[i] = src[i];
  }

  int wv = t >> 6, l = t & 63;
  int rowBase = blockIdx.x * 128 + wv * 32;
  int koff = (l >> 4) * 8;

  // A fragments for 2 m-subtiles (rows +0..15, +16..31)
  bf16x8 a[2][KT];
#pragma unroll
  for (int m = 0; m < 2; m++) {
    int row = rowBase + m * 16 + (l & 15);
    row = min(row, N - 1);  // tail clamp
    if (AF32) {
      const float* A = (const float*)Ain;
      const float* Ar = A + (size_t)row * K;
#pragma unroll
      for (int kt = 0; kt < KT; kt++) {
        const float4* p = (const float4*)(Ar + kt * 32 + koff);
        float4 lo = p[0], hi = p[1];
        bf16x8 av;
        av[0] = (__bf16)lo.x; av[1] = (__bf16)lo.y; av[2] = (__bf16)lo.z; av[3] = (__bf16)lo.w;
        av[4] = (__bf16)hi.x; av[5] = (__bf16)hi.y; av[6] = (__bf16)hi.z; av[7] = (__bf16)hi.w;
        a[m][kt] = av;
      }
    } else {
      const ushort* A = (const ushort*)Ain;
      const ushort* Ar = A + (size_t)row * K;
#pragma unroll
      for (int kt = 0; kt < KT; kt++) a[m][kt] = *(const bf16x8*)(Ar + kt * 32 + koff);
    }
  }

  f32x4 acc[2][8];
#pragma unroll
  for (int m = 0; m < 2; m++)
#pragma unroll
    for (int ct = 0; ct < 8; ct++) { f32x4 z = {0.f, 0.f, 0.f, 0.f}; acc[m][ct] = z; }

  __syncthreads();

#pragma unroll
  for (int ct = 0; ct < 8; ct++) {
#pragma unroll
    for (int kt = 0; kt < KT; kt++) {
      bf16x8 b = *(const bf16x8*)&bs[(size_t)((ct * KT + kt) * 64 + l) * 8];
      acc[0][ct] = __builtin_amdgcn_mfma_f32_16x16x32_bf16(a[0][kt], b, acc[0][ct], 0, 0, 0);
      acc[1][ct] = __builtin_amdgcn_mfma_f32_16x16x32_bf16(a[1][kt], b, acc[1][ct], 0, 0, 0);
    }
  }

  int colD = l & 15;
  __bf16* Cb = (__bf16*)C;
#pragma unroll
  for (int m = 0; m < 2; m++) {
    int rowD = rowBase + m * 16 + (l >> 4) * 4;
#pragma unroll
    for (int ct = 0; ct < 8; ct++) {
#pragma unroll
      for (int r = 0; r < 4; r++) {
        int row = rowD + r;
        if (row < N) Cb[(size_t)row * 128 + ct * 16 + colD] = (__bf16)acc[m][ct][r];
      }
    }
  }
}

// ---------------- aggregation ----------------
template <bool RELU, bool OUTBF>
__global__ __launch_bounds__(256) void agg_k(const ushort* __restrict__ T,
                                             const float* __restrict__ dinv,
                                             const int2* __restrict__ csr,
                                             const int* __restrict__ offsets,
                                             const float* __restrict__ degf,
                                             const float* __restrict__ bias,
                                             void* __restrict__ Hout, int N) {
  int w = threadIdx.x >> 6, l = threadIdx.x & 63;
  int n = blockIdx.x * 4 + w;
  if (n >= N) return;
  float di = dinv[n];
  int off = offsets[n];
  int cnt = (int)degf[n] - 1;
  const uint* Tn = (const uint*)(T + (size_t)n * 128);
  uint selfv = Tn[l];
  float a0 = 0.0f, a1 = 0.0f;

  for (int j0 = 0; j0 < cnt; j0 += 64) {
    int idx = j0 + l;
    int2 e = (idx < cnt) ? csr[off + idx] : make_int2(0, 0);
    int ex = e.x;
    float ew = __int_as_float(e.y);
    int m = min(cnt - j0, 64);
    int j = 0;
    for (; j + 4 <= m; j += 4) {
      int r0 = __shfl(ex, j), r1 = __shfl(ex, j + 1);
      int r2 = __shfl(ex, j + 2), r3 = __shfl(ex, j + 3);
      float w0 = __shfl(ew, j), w1 = __shfl(ew, j + 1);
      float w2 = __shfl(ew, j + 2), w3 = __shfl(ew, j + 3);
      uint v0 = ((const uint*)(T + (size_t)r0 * 128))[l];
      uint v1 = ((const uint*)(T + (size_t)r1 * 128))[l];
      uint v2 = ((const uint*)(T + (size_t)r2 * 128))[l];
      uint v3 = ((const uint*)(T + (size_t)r3 * 128))[l];
      a0 = fmaf(w0, bflo(v0), a0); a1 = fmaf(w0, bfhi(v0), a1);
      a0 = fmaf(w1, bflo(v1), a0); a1 = fmaf(w1, bfhi(v1), a1);
      a0 = fmaf(w2, bflo(v2), a0); a1 = fmaf(w2, bfhi(v2), a1);
      a0 = fmaf(w3, bflo(v3), a0); a1 = fmaf(w3, bfhi(v3), a1);
    }
    for (; j < m; j++) {
      int r = __shfl(ex, j);
      float wj = __shfl(ew, j);
      uint v = ((const uint*)(T + (size_t)r * 128))[l];
      a0 = fmaf(wj, bflo(v), a0);
      a1 = fmaf(wj, bfhi(v), a1);
    }
  }

  float2 b = ((const float2*)bias)[l];
  float o0 = di * a0 + di * di * bflo(selfv) + b.x;
  float o1 = di * a1 + di * di * bfhi(selfv) + b.y;
  if (RELU) { o0 = fmaxf(o0, 0.0f); o1 = fmaxf(o1, 0.0f); }
  if (OUTBF) {
    ((uint*)Hout)[(size_t)n * 64 + l] = packbf(o0, o1);
  } else {
    ((float2*)Hout)[(size_t)n * 64 + l] = make_float2(o0, o1);
  }
}

// ---------------- per-graph boundaries (batch sorted) ----------------
__global__ __launch_bounds__(256) void boundary_k(const int* __restrict__ batch,
                                                  int* __restrict__ gstart,
                                                  int* __restrict__ gend, int N) {
  int i = blockIdx.x * 256 + threadIdx.x;
  if (i >= N) return;
  int b = batch[i];
  if (i == 0 || batch[i - 1] != b) gstart[b] = i;
  if (i == N - 1 || batch[i + 1] != b) gend[b] = i + 1;
}

// ---------------- mean pool: 8 splits per graph ----------------
__global__ __launch_bounds__(128) void pool_k(const float* __restrict__ H,
                                              const int* __restrict__ gstart,
                                              const int* __restrict__ gend,
                                              float* __restrict__ sums) {
  int g = blockIdx.x >> 3, s = blockIdx.x & 7;
  int gs = gstart[g], ge = gend[g];
  int len = ge - gs;
  if (len <= 0) return;
  int chunk = (len + 7) >> 3;
  int r0 = gs + s * chunk;
  int r1 = min(r0 + chunk, ge);
  if (r0 >= r1) return;
  int f = threadIdx.x;
  float local = 0.0f;
  int r = r0;
  for (; r + 4 <= r1; r += 4) {
    float h0 = H[(size_t)r * 128 + f];
    float h1 = H[(size_t)(r + 1) * 128 + f];
    float h2 = H[(size_t)(r + 2) * 128 + f];
    float h3 = H[(size_t)(r + 3) * 128 + f];
    local += (h0 + h1) + (h2 + h3);
  }
  for (; r < r1; r++) local += H[(size_t)r * 128 + f];
  atomicAdd(&sums[g * 128 + f], local);
}

// ---------------- classifier: out[64][2] ----------------
__global__ __launch_bounds__(128) void final_k(const float* __restrict__ sums,
                                               const int* __restrict__ gstart,
                                               const int* __restrict__ gend,
                                               const float* __restrict__ Wc,
                                               const float* __restrict__ bc,
                                               float* __restrict__ out) {
  int t = threadIdx.x;
  int g = t >> 1, c = t & 1;
  float cg = fmaxf((float)(gend[g] - gstart[g]), 1.0f);
  float acc = bc[c];
  for (int f = 0; f < 128; f++) acc += (sums[g * 128 + f] / cg) * Wc[f * 2 + c];
  out[g * 2 + c] = acc;
}

extern "C" void kernel_launch(void* const* d_in, const int* in_sizes, int n_in,
                              void* d_out, int out_size, void* d_ws, size_t ws_size,
                              hipStream_t stream) {
  const float* x = (const float*)d_in[0];
  const int* ei = (const int*)d_in[1];     // [2][E]
  const int* batch = (const int*)d_in[2];  // [N]
  const float* W1 = (const float*)d_in[3];
  const float* b1 = (const float*)d_in[4];
  const float* W2 = (const float*)d_in[5];
  const float* b2 = (const float*)d_in[6];
  const float* W3 = (const float*)d_in[7];
  const float* b3 = (const float*)d_in[8];
  const float* Wc = (const float*)d_in[9];
  const float* bc = (const float*)d_in[10];
  float* out = (float*)d_out;

  int N = in_sizes[0] / 256;
  int E = in_sizes[1] / 2;

  char* ws = (char*)d_ws;
  size_t off = 0;
  auto alloc = [&](size_t bytes) -> void* {
    off = (off + 255) & ~(size_t)255;
    void* p = ws + off;
    off += bytes;
    return p;
  };
  float* degf = (float*)alloc((size_t)N * 4);
  float* dinv = (float*)alloc((size_t)N * 4);
  int* offsets = (int*)alloc((size_t)N * 4);
  int* cursor = (int*)alloc((size_t)N * 4);
  int* blockSums = (int*)alloc(256 * 4);
  int* blockOff = (int*)alloc(256 * 4);
  float* sums = (float*)alloc(64 * 128 * 4);
  int* gstart = (int*)alloc(64 * 4);
  int* gend = (int*)alloc(64 * 4);
  ushort* WTp1 = (ushort*)alloc(256 * 128 * 2);
  ushort* WTp2 = (ushort*)alloc(128 * 128 * 2);
  ushort* WTp3 = (ushort*)alloc(128 * 128 * 2);
  int2* csr = (int2*)alloc((size_t)E * 8);
  ushort* bufT = (ushort*)alloc((size_t)N * 128 * 2);   // GEMM out (bf16)
  ushort* bufHb = (ushort*)alloc((size_t)N * 128 * 2);  // agg out layers 1-2 (bf16)
  float* bufH = (float*)alloc((size_t)N * 128 * 4);     // agg out layer 3 (f32)

  int gN = (N + 255) / 256;
  int gE = (E + 255) / 256;
  int nb = (N + 1023) / 1024;
  int nblk = (N + 127) / 128;

  hipMemsetAsync(sums, 0, 64 * 128 * 4, stream);
  hipMemsetAsync(gstart, 0, 64 * 4, stream);
  hipMemsetAsync(gend, 0, 64 * 4, stream);

  // degrees + dinv
  init_degf<<<gN, 256, 0, stream>>>(degf, N);
  deg_count<<<gE, 256, 0, stream>>>(ei + E, degf, E);
  dinv_k<<<gN, 256, 0, stream>>>(degf, dinv, N);

  // CSR
  scan_local<<<nb, 256, 0, stream>>>(degf, offsets, blockSums, N);
  scan_block<<<1, 128, 0, stream>>>(blockSums, blockOff, nb);
  scan_add<<<gN, 256, 0, stream>>>(offsets, blockOff, N);
  hipMemcpyAsync(cursor, offsets, (size_t)N * 4, hipMemcpyDeviceToDevice, stream);
  fill_csr<<<gE, 256, 0, stream>>>(ei, dinv, cursor, csr, E);

  // graph boundaries + W permutes
  boundary_k<<<gN, 256, 0, stream>>>(batch, gstart, gend, N);
  wtp_k<<<(256 * 128 + 255) / 256, 256, 0, stream>>>(W1, WTp1, 256, 8);
  wtp_k<<<(128 * 128 + 255) / 256, 256, 0, stream>>>(W2, WTp2, 128, 4);
  wtp_k<<<(128 * 128 + 255) / 256, 256, 0, stream>>>(W3, WTp3, 128, 4);

  // layer 1 (A = x, f32 -> bf16 fused)
  mgemm_k<256, true><<<nblk, 256, 0, stream>>>(x, WTp1, bufT, N);
  agg_k<true, true><<<(N + 3) / 4, 256, 0, stream>>>(bufT, dinv, csr, offsets, degf, b1, bufHb, N);
  // layer 2
  mgemm_k<128, false><<<nblk, 256, 0, stream>>>(bufHb, WTp2, bufT, N);
  agg_k<true, true><<<(N + 3) / 4, 256, 0, stream>>>(bufT, dinv, csr, offsets, degf, b2, bufHb, N);
  // layer 3
  mgemm_k<128, false><<<nblk, 256, 0, stream>>>(bufHb, WTp3, bufT, N);
  agg_k<false, false><<<(N + 3) / 4, 256, 0, stream>>>(bufT, dinv, csr, offsets, degf, b3, bufH, N);

  // pool + classifier
  pool_k<<<64 * 8, 128, 0, stream>>>(bufH, gstart, gend, sums);
  final_k<<<1, 128, 0, stream>>>(sums, gstart, gend, Wc, bc, out);
}